// Round 6
// baseline (1342.810 us; speedup 1.0000x reference)
//
#include <hip/hip_runtime.h>
#include <cstdint>
#include <cstddef>

// Problem shape (fixed by reference): B=8, S=2048, D=1024, D_FF=1024
#define BB 8
#define SS 2048
#define DD 1024

typedef unsigned short bf16_t;                                  // raw bf16 bits
typedef __attribute__((ext_vector_type(8))) short bf16x8;       // MFMA A/B frag (4 VGPRs)
typedef __attribute__((ext_vector_type(4))) float f32x4;        // MFMA C/D frag

#define EPI_BF16   0   // C = bf16(acc + bias), optional ReLU  (bf16 LDS-bounce store)
#define EPI_SCORES 1   // C = mask ? acc*scale : -1e9  (f32, LDS-bounce coalesced)
#define EPI_RESID  2   // C = acc + bias + resid       (f32, LDS-bounce coalesced RMW)

__device__ __forceinline__ bf16_t f2bf(float f) {
  union { float f; unsigned u; } v; v.f = f;
  unsigned r = v.u + 0x7FFFu + ((v.u >> 16) & 1u);   // RNE
  return (bf16_t)(r >> 16);
}

// async global->LDS, 16B per lane. LDS dst must be wave-uniform base + lane*16.
__device__ __forceinline__ void async_copy16(const void* g, void* l) {
  auto gp = reinterpret_cast<unsigned int __attribute__((address_space(1)))*>(
      reinterpret_cast<uintptr_t>(g));
  auto lp = reinterpret_cast<unsigned int __attribute__((address_space(3)))*>(
      reinterpret_cast<uintptr_t>(l));
  __builtin_amdgcn_global_load_lds(gp, lp, 16, 0, 0);
}

// ---------------------------------------------------------------------------
// GEMM parameter block
// ---------------------------------------------------------------------------
struct GemmP {
  const bf16_t* A;
  const bf16_t* BT;
  void*         C;
  const float*  bias;   // [<=ldc] or null
  const float*  bias2;  // second-half bias (fused QK) or null
  const float*  resid;  // [Z,M,ldc] f32 (EPI_RESID)
  const int*    mask;   // per-batch mask (EPI_SCORES)
  int Mt, Nt, Z, nchunk;
  int K, lda, ldb, ldc;
  long long sA, sB, sC, sMask;
  float scale;
};

// ---------------------------------------------------------------------------
// 256x256 NT GEMM core: C[M,N] = A[M,K] * BT[N,K]^T, bf16 in, f32 acc.
// BK=64, 512 threads (8 waves, 2x4), per-wave 128x64 out, 16x16x32 MFMA.
// LDS 128 KiB: [2 dbuf][ A: 2 mh-halves 128x64 | B: 2 nh-halves 128x64 ].
// Swizzle: 16B-slot p holds logical slot p^(row&7) (both-sides, rule 21).
// Single barrier per phase; counted vmcnt(4); fragment-reuse order
// (0,0)->(0,1)->(1,1)->(1,0): 24 ds_read_b128/tile. Byte-identical to r3-r5.
// ---------------------------------------------------------------------------
#define MM(i, j, Af, Bf) \
  acc[i][j] = __builtin_amdgcn_mfma_f32_16x16x32_bf16(Af, Bf, acc[i][j], 0, 0, 0)

#define LDA8(D, MH)                                                        \
  { const char* Ah_ = ldsc + (D) * 65536 + (MH) * 16384;                   \
    aF[0] = *(const bf16x8*)(Ah_ + aro +    0 + s0);                       \
    aF[1] = *(const bf16x8*)(Ah_ + aro + 2048 + s0);                       \
    aF[2] = *(const bf16x8*)(Ah_ + aro + 4096 + s0);                       \
    aF[3] = *(const bf16x8*)(Ah_ + aro + 6144 + s0);                       \
    aF[4] = *(const bf16x8*)(Ah_ + aro +    0 + s1);                       \
    aF[5] = *(const bf16x8*)(Ah_ + aro + 2048 + s1);                       \
    aF[6] = *(const bf16x8*)(Ah_ + aro + 4096 + s1);                       \
    aF[7] = *(const bf16x8*)(Ah_ + aro + 6144 + s1); }

#define LDB4(D, NH, BF)                                                    \
  { const char* Bh_ = ldsc + (D) * 65536 + 32768 + (NH) * 16384;           \
    BF[0] = *(const bf16x8*)(Bh_ + bro +    0 + s0);                       \
    BF[1] = *(const bf16x8*)(Bh_ + bro + 2048 + s0);                       \
    BF[2] = *(const bf16x8*)(Bh_ + bro +    0 + s1);                       \
    BF[3] = *(const bf16x8*)(Bh_ + bro + 2048 + s1); }

#define MFMA16(MH, NH, BF)                                                 \
  __builtin_amdgcn_s_setprio(1);                                           \
  MM((MH)*4+0,(NH)*2+0,aF[0],BF[0]); MM((MH)*4+1,(NH)*2+0,aF[1],BF[0]);    \
  MM((MH)*4+2,(NH)*2+0,aF[2],BF[0]); MM((MH)*4+3,(NH)*2+0,aF[3],BF[0]);    \
  MM((MH)*4+0,(NH)*2+1,aF[0],BF[1]); MM((MH)*4+1,(NH)*2+1,aF[1],BF[1]);    \
  MM((MH)*4+2,(NH)*2+1,aF[2],BF[1]); MM((MH)*4+3,(NH)*2+1,aF[3],BF[1]);    \
  MM((MH)*4+0,(NH)*2+0,aF[4],BF[2]); MM((MH)*4+1,(NH)*2+0,aF[5],BF[2]);    \
  MM((MH)*4+2,(NH)*2+0,aF[6],BF[2]); MM((MH)*4+3,(NH)*2+0,aF[7],BF[2]);    \
  MM((MH)*4+0,(NH)*2+1,aF[4],BF[3]); MM((MH)*4+1,(NH)*2+1,aF[5],BF[3]);    \
  MM((MH)*4+2,(NH)*2+1,aF[6],BF[3]); MM((MH)*4+3,(NH)*2+1,aF[7],BF[3]);    \
  __builtin_amdgcn_s_setprio(0);

template <int EPI, bool RELU>
__device__ __forceinline__ void gemm_core(const GemmP p, int b, char* ldsc)
{
  // ---- XCD swizzle: contiguous idx chunk per XCD (b%8 == XCD for grid 256) ----
  const int Cchunk = (p.Z * p.Mt * p.Nt) >> 3;     // tile count divisible by 8
  int idx = (b & 7) * Cchunk + (b >> 3);
  const int per_z = p.Mt * p.Nt;
  const int z = idx / per_z;  idx -= z * per_z;
  const int per_nc = p.Mt * p.nchunk;
  const int nc = idx / per_nc; idx -= nc * per_nc;
  const int mt = idx / p.nchunk;
  const int nin = idx - mt * p.nchunk;
  const int m0 = mt * 256;
  const int n0 = (nc * p.nchunk + nin) * 256;

  const int tid  = threadIdx.x;
  const int wave = tid >> 6;
  const int lane = tid & 63;
  const int wr   = wave >> 2, wc = wave & 3;       // 2 x 4 wave grid
  const int lr   = lane & 15, quad = lane >> 4;

  const bf16_t* Ab = p.A  + (size_t)z * (size_t)p.sA;
  const bf16_t* Bb = p.BT + (size_t)z * (size_t)p.sB;

  f32x4 acc[8][4];
#pragma unroll
  for (int i = 0; i < 8; ++i)
#pragma unroll
    for (int j = 0; j < 4; ++j)
#pragma unroll
      for (int r = 0; r < 4; ++r) acc[i][j][r] = 0.0f;

  // staging geometry, hoisted. Slot p holds logical k-chunk p^(row&7).
  const bf16_t* gA[2]; const bf16_t* gB[2]; char* lA[2]; char* lB[2];
#pragma unroll
  for (int u = 0; u < 2; ++u) {
    const int c = tid + u * 512;
    const int rl = c >> 3;
    const int csw = (((c & 7) ^ (rl & 7)) << 3);                 // swizzled k-elems
    const int rowA = ((rl & 64) << 1) + (rl & 63);               // rows 0..63,128..191
    const int rowB = ((rl & 96) << 1) + (rl & 31);
    gA[u] = Ab + (size_t)(m0 + rowA) * p.lda + csw;
    gB[u] = Bb + (size_t)(n0 + rowB) * p.ldb + csw;
    lA[u] = ldsc + c * 16;
    lB[u] = ldsc + 32768 + c * 16;
  }
  const int ldA64 = p.lda << 6, ldB64 = p.ldb << 5;

  auto stageA = [&](int d, int mh, int kt) {
    const int go = mh * ldA64 + kt;
    const int lo = d * 65536 + mh * 16384;
#pragma unroll
    for (int u = 0; u < 2; ++u) async_copy16(gA[u] + go, lA[u] + lo);
  };
  auto stageB = [&](int d, int nh, int kt) {
    const int go = nh * ldB64 + kt;
    const int lo = d * 65536 + nh * 16384;
#pragma unroll
    for (int u = 0; u < 2; ++u) async_copy16(gB[u] + go, lB[u] + lo);
  };

  // ds_read addressing: logical slot s = ks*4+quad; physical = s^(lr&7)
  const int s0  = ((quad ^ (lr & 7)) << 4);
  const int s1  = s0 ^ 64;
  const int aro = (wr * 64 + lr) << 7;
  const int bro = (wc * 32 + lr) << 7;

  bf16x8 aF[8];
  bf16x8 bF0[4], bF1[4];

  const int NT = p.K >> 6;

  // ---- prologue: tile0 (4 halves) + tile1 (A-mh0, B-nh0) ----
  stageA(0, 0, 0); stageA(0, 1, 0); stageB(0, 0, 0); stageB(0, 1, 0);
  if (NT > 1) {
    stageA(1, 0, 64); stageB(1, 0, 64);
    asm volatile("s_waitcnt vmcnt(4)" ::: "memory");
  } else {
    asm volatile("s_waitcnt vmcnt(0)" ::: "memory");
  }
  __builtin_amdgcn_s_barrier();

#pragma unroll 2
  for (int t = 0; t < NT; ++t) {
    const int d  = t & 1;
    const int k1 = (t + 1) << 6;
    const int k2 = (t + 2) << 6;

    LDA8(d, 0); LDB4(d, 0, bF0);
    if (t + 1 < NT) stageA(d ^ 1, 1, k1);
    __builtin_amdgcn_s_barrier();
    MFMA16(0, 0, bF0);

    LDB4(d, 1, bF1);
    if (t + 1 < NT) stageB(d ^ 1, 1, k1);
    __builtin_amdgcn_s_barrier();
    MFMA16(0, 1, bF1);

    LDA8(d, 1);
    if (t + 2 < NT) stageA(d, 0, k2);
    __builtin_amdgcn_s_barrier();
    MFMA16(1, 1, bF1);

    if (t + 2 < NT) {
      stageB(d, 0, k2);
      asm volatile("s_waitcnt vmcnt(4)" ::: "memory");
    } else {
      asm volatile("s_waitcnt vmcnt(0)" ::: "memory");
    }
    __builtin_amdgcn_s_barrier();
    MFMA16(1, 0, bF0);
  }

  // ---- epilogue ----  (C/D layout: col = lane&15, row = quad*4 + r)
  if constexpr (EPI == EPI_BF16) {
    // bf16 LDS-bounce. Per-wave 16KB [128m][64n], 16B-chunk XOR swizzle by m&7.
    char* Wb = ldsc + wave * 16384;
#pragma unroll
    for (int i = 0; i < 8; ++i) {
      const int mb = (i >> 2) * 64 + (i & 3) * 16 + quad * 4;     // + r
#pragma unroll
      for (int j = 0; j < 4; ++j) {
        const int nl = (j >> 1) * 32 + (j & 1) * 16 + lr;         // 0..63
        const int gn = n0 + wc * 64 + nl;
        const float bv = (p.bias2 && gn >= 1024) ? p.bias2[gn - 1024]
                       : (p.bias ? p.bias[gn] : 0.0f);
#pragma unroll
        for (int r = 0; r < 4; ++r) {
          float v = acc[i][j][r] + bv;
          if (RELU) v = fmaxf(v, 0.0f);
          const int m = mb + r;
          const int nb = nl * 2;
          const int phys = (m << 7) + (((nb & ~15) ^ ((m & 7) << 4)) | (nb & 15));
          *(bf16_t*)(Wb + phys) = f2bf(v);
        }
      }
    }
    asm volatile("s_waitcnt lgkmcnt(0)" ::: "memory");
    bf16_t* Cb = (bf16_t*)p.C + (size_t)z * (size_t)p.sC
               + (size_t)(m0 + wr * 128) * p.ldc + (n0 + wc * 64);
#pragma unroll
    for (int q = 0; q < 16; ++q) {
      const int m = q * 8 + (lane >> 3);
      const int c = lane & 7;
      const bf16x8 vv = *(const bf16x8*)(Wb + (m << 7) + (((c ^ (m & 7)) << 4)));
      *(bf16x8*)(Cb + (size_t)m * p.ldc + c * 8) = vv;
    }
    __builtin_amdgcn_s_barrier();   // LDS reuse barrier before caller's next stage
  } else {
    // f32 LDS-bounce, two half-passes of [64m][64n] f32 per wave (16KB).
    char* Wb = ldsc + wave * 16384;
#pragma unroll
    for (int hh = 0; hh < 2; ++hh) {
#pragma unroll
      for (int ii = 0; ii < 4; ++ii) {
        const int i = hh * 4 + ii;
        const int ml = ii * 16 + quad * 4;                        // + r
#pragma unroll
        for (int j = 0; j < 4; ++j) {
          const int nl = (j >> 1) * 32 + (j & 1) * 16 + lr;       // 0..63
          const int gn = n0 + wc * 64 + nl;
          float addv = 0.0f; int mk = 1;
          if constexpr (EPI == EPI_RESID) addv = p.bias ? p.bias[gn] : 0.0f;
          if constexpr (EPI == EPI_SCORES)
            mk = p.mask[(size_t)z * (size_t)p.sMask + gn];
#pragma unroll
          for (int r = 0; r < 4; ++r) {
            const int m = ml + r;
            float v = acc[i][j][r];
            if constexpr (EPI == EPI_SCORES) v = mk ? v * p.scale : -1e9f;
            else v += addv;
            const int nph = nl ^ (((m >> 2) & 3) << 2);
            *(float*)(Wb + m * 256 + nph * 4) = v;
          }
        }
      }
      asm volatile("s_waitcnt lgkmcnt(0)" ::: "memory");
      const int mb = m0 + wr * 128 + hh * 64;
      const int gn0 = n0 + wc * 64 + lr * 4;
#pragma unroll
      for (int q = 0; q < 16; ++q) {
        const int m = q * 4 + quad;
        const int nph = (lr * 4) ^ (((m >> 2) & 3) << 2);
        f32x4 v = *(const f32x4*)(Wb + m * 256 + nph * 4);
        const size_t off = (size_t)z * (size_t)p.sC
                         + (size_t)(mb + m) * p.ldc + gn0;
        if constexpr (EPI == EPI_RESID) {
          const f32x4 rv = *(const f32x4*)(p.resid + off);
          v = v + rv;
        }
        *(f32x4*)((float*)p.C + off) = v;
      }
      if (hh == 0) { asm volatile("s_waitcnt lgkmcnt(0)" ::: "memory"); }
    }
    __builtin_amdgcn_s_barrier();   // LDS reuse barrier before caller's next stage
  }
}

// ---------------------------------------------------------------------------
// 512-thread LayerNorm row (D=1024: 2 floats/thread), 8-wave LDS reduce.
// ---------------------------------------------------------------------------
__device__ __forceinline__ void ln512(const float* __restrict__ x,
                                      const float* __restrict__ g,
                                      const float* __restrict__ b,
                                      bf16_t* __restrict__ out,
                                      int row, int t, float* red)
{
  const int wave = t >> 6, lane = t & 63;
  const float2 v = ((const float2*)(x + (size_t)row * DD))[t];
  float s = v.x + v.y;
#pragma unroll
  for (int o = 32; o > 0; o >>= 1) s += __shfl_down(s, o);
  if (lane == 0) red[wave] = s;
  __syncthreads();
  const float mu = (red[0]+red[1]+red[2]+red[3]+red[4]+red[5]+red[6]+red[7]) * (1.0f/DD);
  const float d0 = v.x - mu, d1 = v.y - mu;
  float ss = d0*d0 + d1*d1;
#pragma unroll
  for (int o = 32; o > 0; o >>= 1) ss += __shfl_down(ss, o);
  if (lane == 0) red[8+wave] = ss;
  __syncthreads();
  const float var = (red[8]+red[9]+red[10]+red[11]+red[12]+red[13]+red[14]+red[15]) * (1.0f/DD);
  const float rs = rsqrtf(var + 1e-5f);
  const float2 gg = ((const float2*)g)[t];
  const float2 bb = ((const float2*)b)[t];
  const unsigned lo = f2bf(d0*rs*gg.x + bb.x);
  const unsigned hi = f2bf(d1*rs*gg.y + bb.y);
  ((unsigned*)(out + (size_t)row * DD))[t] = (hi << 16) | lo;
  __syncthreads();   // red reuse next iteration
}

// ---------------------------------------------------------------------------
// 512-thread softmax row (S=2048: float4/thread); f32 in-place + bf16 copy.
// ---------------------------------------------------------------------------
__device__ __forceinline__ void softmax512(float* __restrict__ w,
                                           bf16_t* __restrict__ wb,
                                           int row, int t, float* red)
{
  float* p = w + (size_t)row * SS;
  const int wave = t >> 6, lane = t & 63;
  float4 v = ((float4*)p)[t];
  float m = fmaxf(fmaxf(v.x, v.y), fmaxf(v.z, v.w));
#pragma unroll
  for (int o = 32; o > 0; o >>= 1) m = fmaxf(m, __shfl_down(m, o));
  if (lane == 0) red[wave] = m;
  __syncthreads();
  m = fmaxf(fmaxf(fmaxf(red[0],red[1]),fmaxf(red[2],red[3])),
            fmaxf(fmaxf(red[4],red[5]),fmaxf(red[6],red[7])));
  v.x = __expf(v.x - m); v.y = __expf(v.y - m);
  v.z = __expf(v.z - m); v.w = __expf(v.w - m);
  float s = v.x + v.y + v.z + v.w;
#pragma unroll
  for (int o = 32; o > 0; o >>= 1) s += __shfl_down(s, o);
  if (lane == 0) red[8+wave] = s;
  __syncthreads();
  const float inv = 1.0f / (red[8]+red[9]+red[10]+red[11]+red[12]+red[13]+red[14]+red[15]);
  v.x *= inv; v.y *= inv; v.z *= inv; v.w *= inv;
  ((float4*)p)[t] = v;
  uint2 u;
  u.x = ((unsigned)f2bf(v.y) << 16) | (unsigned)f2bf(v.x);
  u.y = ((unsigned)f2bf(v.w) << 16) | (unsigned)f2bf(v.z);
  ((uint2*)(wb + (size_t)row * SS))[t] = u;
  __syncthreads();   // red reuse next iteration
}

// ---------------------------------------------------------------------------
// 32x32 tile transpose f32 -> bf16 (256-thread sub-body, tx in [0,32), ty [0,8))
// ---------------------------------------------------------------------------
__device__ __forceinline__ void transpose_body(const float* __restrict__ in,
                                               bf16_t* __restrict__ out,
                                               int xb, int yb,
                                               int tx, int ty, float* tile)
{
  const int c0 = xb * 32, r0 = yb * 32;
#pragma unroll
  for (int k = 0; k < 32; k += 8)
    tile[(ty + k) * 33 + tx] = in[(size_t)(r0 + ty + k) * DD + (c0 + tx)];
  __syncthreads();
#pragma unroll
  for (int k = 0; k < 32; k += 8)
    out[(size_t)(c0 + ty + k) * DD + (r0 + tx)] = f2bf(tile[tx * 33 + ty + k]);
}

// ---------------------------------------------------------------------------
// Software grid barrier: all 256 blocks provably co-resident (128KB LDS ->
// 1 block/CU, 256 CUs). Monotonic counter; device-scope atomics + fences (G16).
// ---------------------------------------------------------------------------
__device__ __forceinline__ void gsync(unsigned* bar, unsigned target)
{
  __syncthreads();
  if (threadIdx.x == 0) {
    __threadfence();   // release: prior global writes visible device-wide
    __hip_atomic_fetch_add(bar, 1u, __ATOMIC_ACQ_REL, __HIP_MEMORY_SCOPE_AGENT);
    while (__hip_atomic_load(bar, __ATOMIC_ACQUIRE, __HIP_MEMORY_SCOPE_AGENT) < target)
      __builtin_amdgcn_s_sleep(2);
    __threadfence();   // acquire side
  }
  __syncthreads();
}

// ---------------------------------------------------------------------------
// Mega persistent kernel: whole transformer block, grid MUST be exactly 256.
// ---------------------------------------------------------------------------
struct MegaP {
  const float *Wq, *Wk, *Wo, *W1, *W2;
  bf16_t *WqkT, *WoT, *W1T, *W2T;
  const float *x, *ln1g, *ln1b; bf16_t *xn;
  GemmP qk, sc, kwo, wkwo, ff1, ff2;
  float *wout; bf16_t *wbf;
  const float *x2; const float *ln2g, *ln2b; bf16_t *xn2;
  unsigned* bar;
};

__global__ __launch_bounds__(512, 2)
void mega_kernel(MegaP P)
{
  __shared__ __align__(16) char lds[131072];
  const int bid = blockIdx.x;
  const int tid = threadIdx.x;
  float* redf = (float*)lds;

  // ---- S1: 5 weight transposes (5120 tiles, 2/block/iter) + LN1 (16384 rows)
  {
    const int half = tid >> 8, t = tid & 255;
    float* tile_s = (float*)lds + half * (32 * 33);
    for (int it = 0; it < 10; ++it) {
      const int tt = (it * 256 + bid) * 2 + half;          // 0..5119
      const int wi = tt >> 10, rem = tt & 1023;
      const float* src = wi==0?P.Wq : wi==1?P.Wk : wi==2?P.Wo : wi==3?P.W1 : P.W2;
      bf16_t* dst = wi==0?P.WqkT : wi==1?(P.WqkT+(size_t)DD*DD)
                  : wi==2?P.WoT : wi==3?P.W1T : P.W2T;
      transpose_body(src, dst, rem & 31, rem >> 5, t & 31, t >> 5, tile_s);
      __syncthreads();
    }
    for (int r = bid; r < BB*SS; r += 256) ln512(P.x, P.ln1g, P.ln1b, P.xn, r, tid, redf);
  }
  gsync(P.bar, 256);

  // ---- S2: QK = xn @ [Wq|Wk] + [bq|bk]  (512 tiles)
  for (int i = bid; i < 512; i += 256) gemm_core<EPI_BF16, false>(P.qk, i, lds);
  gsync(P.bar, 512);

  // ---- S3: scores (512 tiles) + KWoT = (K@Wo)^T (256 tiles)
  for (int i = bid; i < 768; i += 256) {
    if (i < 512) gemm_core<EPI_SCORES, false>(P.sc, i, lds);
    else         gemm_core<EPI_BF16,   false>(P.kwo, i - 512, lds);
  }
  gsync(P.bar, 768);

  // ---- S4: softmax rows -> wout f32 (required output) + wbf bf16
  for (int r = bid; r < BB*SS; r += 256) softmax512(P.wout, P.wbf, r, tid, redf);
  gsync(P.bar, 1024);

  // ---- S5: x2 = x + w @ KWoT^T + bo  (256 tiles)
  gemm_core<EPI_RESID, false>(P.wkwo, bid, lds);
  gsync(P.bar, 1280);

  // ---- S6: xn2 = LN2(x2)
  for (int r = bid; r < BB*SS; r += 256) ln512(P.x2, P.ln2g, P.ln2b, P.xn2, r, tid, redf);
  gsync(P.bar, 1536);

  // ---- S7: h = relu(xn2@W1 + b1)  (256 tiles)
  gemm_core<EPI_BF16, true>(P.ff1, bid, lds);
  gsync(P.bar, 1792);

  // ---- S8: out = x2 + h@W2 + b2  (256 tiles)
  gemm_core<EPI_RESID, false>(P.ff2, bid, lds);
}

// ---------------------------------------------------------------------------
extern "C" void kernel_launch(void* const* d_in, const int* in_sizes, int n_in,
                              void* d_out, int out_size, void* d_ws, size_t ws_size,
                              hipStream_t stream)
{
  const float* x    = (const float*)d_in[0];
  const int*   mask = (const int*)d_in[1];
  const float* ln1g = (const float*)d_in[2];
  const float* ln1b = (const float*)d_in[3];
  const float* Wq   = (const float*)d_in[4];
  const float* bq   = (const float*)d_in[5];
  const float* Wk   = (const float*)d_in[6];
  const float* bk   = (const float*)d_in[7];
  const float* Wo   = (const float*)d_in[8];
  const float* bo   = (const float*)d_in[9];
  const float* ln2g = (const float*)d_in[10];
  const float* ln2b = (const float*)d_in[11];
  const float* W1   = (const float*)d_in[12];
  const float* b1   = (const float*)d_in[13];
  const float* W2   = (const float*)d_in[14];
  const float* b2   = (const float*)d_in[15];

  float* out  = (float*)d_out;                       // (B,S,D) f32, 64MB
  float* wout = out + (size_t)BB * SS * DD;          // (B,S,S) f32, 128MB

  char* ws = (char*)d_ws;
  size_t off = 0;
  auto alloc = [&](size_t bytes) {
    char* p = ws + off; off += (bytes + 255) & ~(size_t)255; return p;
  };
  bf16_t* WqkT = (bf16_t*)alloc((size_t)2 * DD * DD * 2);   // [2048,1024] = WqT ; WkT
  bf16_t* WoT  = (bf16_t*)alloc((size_t)DD * DD * 2);
  bf16_t* W1T  = (bf16_t*)alloc((size_t)DD * DD * 2);
  bf16_t* W2T  = (bf16_t*)alloc((size_t)DD * DD * 2);
  bf16_t* QKb  = (bf16_t*)alloc((size_t)BB * SS * 2 * DD * 2);  // [16384,2048] bf16
  char*   Rwb  = alloc((size_t)64 * 1024 * 1024);               // wbf -> xn2+h
  bf16_t* KWoT = (bf16_t*)alloc((size_t)BB * SS * DD * 2);      // (K@Wo)^T [B,1024,2048]
  unsigned* bar = (unsigned*)alloc(256);

  bf16_t* wbf = (bf16_t*)Rwb;                      // (B,S,S) bf16, dies after w@KWo
  bf16_t* xn2 = (bf16_t*)Rwb;                      // (B*S,D) bf16 (after wbf dead)
  bf16_t* h   = (bf16_t*)(Rwb + (size_t)32 * 1024 * 1024);  // (B*S,D_FF) bf16

  bf16_t* xn = (bf16_t*)wout;                      // (B*S,D) bf16, dies after QK
  float*  x2 = out;                                // (B*S,D) f32

  const long long SD  = (long long)SS * DD;
  const long long S2  = (long long)SS * SS;
  const long long QKs = (long long)SS * 2 * DD;

  hipMemsetAsync(bar, 0, 256, stream);

  MegaP P;
  P.Wq = Wq; P.Wk = Wk; P.Wo = Wo; P.W1 = W1; P.W2 = W2;
  P.WqkT = WqkT; P.WoT = WoT; P.W1T = W1T; P.W2T = W2T;
  P.x = x; P.ln1g = ln1g; P.ln1b = ln1b; P.xn = xn;
  P.qk   = GemmP{xn, WqkT, QKb, bq, bk, nullptr, nullptr,
                 64, 8, 1, 8, DD, DD, DD, 2 * DD, 0, 0, 0, 0, 1.0f};
  P.sc   = GemmP{QKb, QKb + DD, wout, nullptr, nullptr, nullptr, mask,
                 8, 8, BB, 8, DD, 2 * DD, 2 * DD, SS, QKs, QKs, S2, SS, 0.03125f};
  P.kwo  = GemmP{WoT, QKb + DD, KWoT, nullptr, nullptr, nullptr, nullptr,
                 4, 8, BB, 8, DD, DD, 2 * DD, SS, 0, QKs, SD, 0, 1.0f};
  P.wkwo = GemmP{wbf, KWoT, x2, bo, nullptr, x, nullptr,
                 8, 4, BB, 4, SS, SS, SS, DD, S2, SD, SD, 0, 1.0f};
  P.ff1  = GemmP{xn2, W1T, h, b1, nullptr, nullptr, nullptr,
                 64, 4, 1, 4, DD, DD, DD, DD, 0, 0, 0, 0, 1.0f};
  P.ff2  = GemmP{h, W2T, out, b2, nullptr, x2, nullptr,
                 64, 4, 1, 4, DD, DD, DD, DD, 0, 0, 0, 0, 1.0f};
  P.wout = wout; P.wbf = wbf;
  P.x2 = x2; P.ln2g = ln2g; P.ln2b = ln2b; P.xn2 = xn2;
  P.bar = bar;

  mega_kernel<<<dim3(256), dim3(512), 0, stream>>>(P);
}